// Round 1
// baseline (8295.490 us; speedup 1.0000x reference)
//
#include <hip/hip_runtime.h>
#include <math.h>

#define BB 2
#define HH 16
#define SS 2048
#define DD 64

// Exact integer-threshold version of the T5 relative-position bucket
// (bidirectional, num_buckets=32 -> half=16, max_exact=8, max_distance=128).
// val_if_large = 8 + trunc(2*log2(n/8)); boundaries at n = 8*2^(j/2):
// j>=1 @ n>=12, j>=2 @ 16, j>=3 @ 23, j>=4 @ 32, j>=5 @ 46, j>=6 @ 64, j>=7 @ 91.
// n>=128 gives val>=16 but reference clamps to 15, which the 7-threshold sum also yields.
__device__ __forceinline__ int rel_bucket(int cpq, int mpk) {
    int n = cpq - mpk;            // n = -(mem - ctx)
    int ret = 0;
    if (n < 0) { ret = 16; n = -n; }
    int v;
    if (n < 8) {
        v = n;
    } else {
        int j = (n >= 12) + (n >= 16) + (n >= 23) + (n >= 32) +
                (n >= 46) + (n >= 64) + (n >= 91);
        v = 8 + j;   // j<=7 -> v<=15 (matches min(val,15))
    }
    return ret + v;
}

__launch_bounds__(256)
__global__ void attn_row_kernel(const float* __restrict__ qg,
                                const float* __restrict__ kg,
                                const float* __restrict__ vg,
                                const float* __restrict__ bw,
                                const int*   __restrict__ cp,
                                const int*   __restrict__ mp,
                                const int*   __restrict__ mask,
                                float* __restrict__ o_out,
                                float* __restrict__ a_out,
                                float* __restrict__ p_out) {
    const int bid = blockIdx.x;            // (b*H + h)*S + qi
    const int qi  = bid & (SS - 1);
    const int h   = (bid >> 11) & (HH - 1);
    const int b   = bid >> 15;
    const int tid = threadIdx.x;

    const int bh = b * HH + h;
    const float* qrow  = qg + ((size_t)bh * SS + qi) * DD;
    const float* Kbase = kg + (size_t)bh * SS * DD;
    const float* Vbase = vg + (size_t)bh * SS * DD;
    const int*   mrow  = mask + ((size_t)b * SS + qi) * SS;
    float* arow = a_out + ((size_t)bh * SS + qi) * SS;
    float* prow = p_out + ((size_t)bh * SS + qi) * SS;

    // q row in registers (same 64 floats for all threads -> broadcast loads)
    float4 q4[16];
    const float4* qr4 = (const float4*)qrow;
    #pragma unroll
    for (int i = 0; i < 16; ++i) q4[i] = qr4[i];

    const int cpq = cp[b * SS + qi];

    __shared__ float p_lds[SS];      // 8 KB: probabilities for PV stage
    __shared__ float redmax[4];
    __shared__ float redsum[4];
    __shared__ float part[256];      // PV partial reduction

    float sc[8];
    float pbv[8];
    float mx = -INFINITY;
    #pragma unroll
    for (int j = 0; j < 8; ++j) {
        const int c = tid + j * 256;
        const float4* kv = (const float4*)(Kbase + (size_t)c * DD);
        float acc = 0.f;
        #pragma unroll
        for (int dd = 0; dd < 16; ++dd) {
            const float4 k4 = kv[dd];
            acc += q4[dd].x * k4.x + q4[dd].y * k4.y +
                   q4[dd].z * k4.z + q4[dd].w * k4.w;
        }
        const int bucket = rel_bucket(cpq, mp[b * SS + c]);
        const float pb = bw[bucket * HH + h];
        pbv[j] = pb;
        float s = acc * 0.125f + pb;          // / TEMPERATURE(8) + bias
        if (mrow[c] != 0) s = -1.0e9f;        // True = masked out
        sc[j] = s;
        mx = fmaxf(mx, s);
    }

    // block max (wave64 shuffle reduce, then 4-wave LDS combine)
    #pragma unroll
    for (int off = 32; off >= 1; off >>= 1)
        mx = fmaxf(mx, __shfl_xor(mx, off, 64));
    if ((tid & 63) == 0) redmax[tid >> 6] = mx;
    __syncthreads();
    const float m = fmaxf(fmaxf(redmax[0], redmax[1]), fmaxf(redmax[2], redmax[3]));

    float ev[8];
    float se = 0.f;
    #pragma unroll
    for (int j = 0; j < 8; ++j) {
        ev[j] = expf(sc[j] - m);
        se += ev[j];
    }
    #pragma unroll
    for (int off = 32; off >= 1; off >>= 1)
        se += __shfl_xor(se, off, 64);
    if ((tid & 63) == 0) redsum[tid >> 6] = se;
    __syncthreads();
    const float inv = 1.0f / (redsum[0] + redsum[1] + redsum[2] + redsum[3]);

    #pragma unroll
    for (int j = 0; j < 8; ++j) {
        const int c = tid + j * 256;
        const float p = ev[j] * inv;
        arow[c] = p;          // coalesced
        prow[c] = pbv[j];     // coalesced
        p_lds[c] = p;
    }
    __syncthreads();

    // PV: thread t handles d = t&63, k-chunk = t>>6 (4 chunks x 512)
    const int d  = tid & 63;
    const int ch = tid >> 6;
    float accv = 0.f;
    const float* vp = Vbase + (size_t)(ch * 512) * DD + d;
    #pragma unroll 8
    for (int c = 0; c < 512; ++c) {
        accv += p_lds[ch * 512 + c] * vp[(size_t)c * DD];
    }
    part[tid] = accv;
    __syncthreads();
    if (tid < 64) {
        const float r = part[tid] + part[64 + tid] + part[128 + tid] + part[192 + tid];
        o_out[((size_t)bh * SS + qi) * DD + tid] = r;
    }
}

extern "C" void kernel_launch(void* const* d_in, const int* in_sizes, int n_in,
                              void* d_out, int out_size, void* d_ws, size_t ws_size,
                              hipStream_t stream) {
    const float* q  = (const float*)d_in[0];
    const float* k  = (const float*)d_in[1];
    const float* v  = (const float*)d_in[2];
    const float* bw = (const float*)d_in[3];
    const int*   cp = (const int*)d_in[4];
    const int*   mp = (const int*)d_in[5];
    const int*   mask = (const int*)d_in[6];

    float* o_out = (float*)d_out;                                   // [B,H,S,D]
    float* a_out = o_out + (size_t)BB * HH * SS * DD;               // [B,H,S,S]
    float* p_out = a_out + (size_t)BB * HH * SS * SS;               // [B,H,S,S]

    const int grid = BB * HH * SS;   // one block per (b,h,q) row
    attn_row_kernel<<<grid, 256, 0, stream>>>(q, k, v, bw, cp, mp, mask,
                                              o_out, a_out, p_out);
}

// Round 2
// 2302.090 us; speedup vs baseline: 3.6035x; 3.6035x over previous
//
#include <hip/hip_runtime.h>
#include <math.h>

#define BB 2
#define HH 16
#define SS 2048
#define DD 64
#define TQ 16
#define STRIDE 2052   // score strip row stride (floats): %4==0 for b128, %32==4 to break bank conflicts

typedef __attribute__((ext_vector_type(8))) short bf16x8;
typedef __attribute__((ext_vector_type(4))) float f32x4;

__device__ __forceinline__ unsigned short f2bf(float f) {
    unsigned u = __float_as_uint(f);
    u += 0x7FFF + ((u >> 16) & 1);   // RNE
    return (unsigned short)(u >> 16);
}

// Exact integer-threshold T5 bucket (bidirectional, 32 buckets, max_distance=128).
__device__ __forceinline__ int rel_bucket(int cpq, int mpk) {
    int n = cpq - mpk;            // n = -(mem - ctx)
    int ret = 0;
    if (n < 0) { ret = 16; n = -n; }
    int v;
    if (n < 8) v = n;
    else {
        int j = (n >= 12) + (n >= 16) + (n >= 23) + (n >= 32) +
                (n >= 46) + (n >= 64) + (n >= 91);
        v = 8 + j;
    }
    return ret + v;
}

__launch_bounds__(512, 1)
__global__ void attn_tile_kernel(const float* __restrict__ qg,
                                 const float* __restrict__ kg,
                                 const float* __restrict__ vg,
                                 const float* __restrict__ bw,
                                 const int*   __restrict__ cp,
                                 const int*   __restrict__ mp,
                                 const int*   __restrict__ mask,
                                 float* __restrict__ o_out,
                                 float* __restrict__ a_out,
                                 float* __restrict__ p_out) {
    __shared__ __align__(16) float strip[TQ * STRIDE];        // 131328 B
    __shared__ __align__(16) float partials[4 * TQ * DD];     // 16384 B
    __shared__ __align__(16) unsigned short q_lds[TQ * 72];   // 2304 B (row pad 64->72)
    __shared__ float bwh[32];
    __shared__ float invl[TQ];

    const int tid = threadIdx.x;
    // XCD-aware swizzle: 4 heads per XCD share K/V in L2; q-tiles grouped so the
    // 4 heads of one q-tile run concurrently (mask rows shared across heads).
    const int x   = blockIdx.x;
    const int xcd = x & 7;
    const int s_  = x >> 3;              // 0..511 per XCD
    const int bh  = xcd * 4 + (s_ & 3);  // 0..31
    const int qt  = s_ >> 2;             // 0..127
    const int b   = bh >> 4;
    const int h   = bh & 15;
    const int q0  = qt * TQ;

    const float* Kbase = kg + (size_t)bh * SS * DD;
    const float* Vbase = vg + (size_t)bh * SS * DD;

    // ---- stage Q tile (bf16) + bias column ----
    {
        const float* Qrow = qg + ((size_t)bh * SS + q0) * DD;
        for (int e = tid; e < TQ * DD; e += 512) {
            int r = e >> 6, d = e & 63;
            q_lds[r * 72 + d] = f2bf(Qrow[r * DD + d]);
        }
        if (tid < 32) bwh[tid] = bw[tid * HH + h];
    }
    __syncthreads();

    const int lane = tid & 63;
    const int wave = tid >> 6;
    const int quad = lane >> 4;
    const int l16  = lane & 15;

    // ---- Phase A: QK^T via MFMA 16x16x32 bf16 -> LDS strip (raw scores) ----
    {
        bf16x8 a0 = *(const bf16x8*)&q_lds[l16 * 72 + quad * 8];        // dims 0..31
        bf16x8 a1 = *(const bf16x8*)&q_lds[l16 * 72 + 32 + quad * 8];   // dims 32..63
        for (int ii = 0; ii < 16; ++ii) {
            const int kt  = wave * 16 + ii;         // key tile of 16
            const int key = kt * 16 + l16;
            const float* kp = Kbase + (size_t)key * DD + quad * 8;
            float4 f0 = *(const float4*)(kp);
            float4 f1 = *(const float4*)(kp + 4);
            float4 f2 = *(const float4*)(kp + 32);
            float4 f3 = *(const float4*)(kp + 36);
            union { bf16x8 v; unsigned short u[8]; } b0, b1;
            b0.u[0] = f2bf(f0.x); b0.u[1] = f2bf(f0.y);
            b0.u[2] = f2bf(f0.z); b0.u[3] = f2bf(f0.w);
            b0.u[4] = f2bf(f1.x); b0.u[5] = f2bf(f1.y);
            b0.u[6] = f2bf(f1.z); b0.u[7] = f2bf(f1.w);
            b1.u[0] = f2bf(f2.x); b1.u[1] = f2bf(f2.y);
            b1.u[2] = f2bf(f2.z); b1.u[3] = f2bf(f2.w);
            b1.u[4] = f2bf(f3.x); b1.u[5] = f2bf(f3.y);
            b1.u[6] = f2bf(f3.z); b1.u[7] = f2bf(f3.w);
            f32x4 acc = {0.f, 0.f, 0.f, 0.f};
            acc = __builtin_amdgcn_mfma_f32_16x16x32_bf16(a0, b0.v, acc, 0, 0, 0);
            acc = __builtin_amdgcn_mfma_f32_16x16x32_bf16(a1, b1.v, acc, 0, 0, 0);
            // C layout: row=(lane>>4)*4+reg, col=lane&15
            const int col = kt * 16 + l16;
            const int rb  = quad * 4;
            strip[(rb + 0) * STRIDE + col] = acc[0];
            strip[(rb + 1) * STRIDE + col] = acc[1];
            strip[(rb + 2) * STRIDE + col] = acc[2];
            strip[(rb + 3) * STRIDE + col] = acc[3];
        }
    }
    __syncthreads();

    // ---- Phase B/C: scale+bias+mask, row max, exp, sum; write bias out ----
    {
        const int r  = tid >> 5;
        const int i  = tid & 31;
        const int qi = q0 + r;
        const int cpq = cp[b * SS + qi];
        const int* mrow = mask + ((size_t)b * SS + qi) * SS;
        const int* mpb  = mp + b * SS;
        float* prow = p_out + ((size_t)bh * SS + qi) * SS;
        float* srow = strip + r * STRIDE;
        float mx = -3.0e38f;
        for (int j = 0; j < 64; ++j) {
            const int c = i + 32 * j;
            const int bu = rel_bucket(cpq, mpb[c]);
            const float pb = bwh[bu];
            float s = srow[c] * 0.125f + pb;
            if (mrow[c] != 0) s = -1.0e9f;
            srow[c] = s;
            prow[c] = pb;
            mx = fmaxf(mx, s);
        }
        #pragma unroll
        for (int off = 16; off >= 1; off >>= 1)
            mx = fmaxf(mx, __shfl_xor(mx, off, 32));
        float sum = 0.f;
        for (int j = 0; j < 64; ++j) {
            const int c = i + 32 * j;
            const float e = __expf(srow[c] - mx);
            srow[c] = e;
            sum += e;
        }
        #pragma unroll
        for (int off = 16; off >= 1; off >>= 1)
            sum += __shfl_xor(sum, off, 32);
        if (i == 0) invl[r] = 1.0f / sum;
    }
    __syncthreads();

    // ---- Phase D: write attn = e * inv_l (coalesced, 2 KB per iter) ----
    {
        float* abase = a_out + ((size_t)bh * SS + q0) * SS;
        for (int r = 0; r < TQ; ++r) {
            const float iv = invl[r];
            const float* srow = strip + r * STRIDE;
            float* arow = abase + (size_t)r * SS;
            #pragma unroll
            for (int j2 = 0; j2 < 4; ++j2) {
                const int c = tid + 512 * j2;
                arow[c] = srow[c] * iv;
            }
        }
    }

    // ---- Phase E: PV (VALU fp32). wave -> (key quarter, row half of 8) ----
    {
        const int kc = wave & 3;
        const int rb = (wave >> 2) * 8;
        const int d  = lane;
        float acc[8];
        #pragma unroll
        for (int rr = 0; rr < 8; ++rr) acc[rr] = 0.f;
        const int cbeg = kc * 512;
        for (int c0 = cbeg; c0 < cbeg + 512; c0 += 4) {
            f32x4 e[8];
            #pragma unroll
            for (int rr = 0; rr < 8; ++rr)
                e[rr] = *(const f32x4*)&strip[(rb + rr) * STRIDE + c0];  // broadcast
            #pragma unroll
            for (int u = 0; u < 4; ++u) {
                const float vv = Vbase[(size_t)(c0 + u) * DD + d];       // coalesced
                #pragma unroll
                for (int rr = 0; rr < 8; ++rr)
                    acc[rr] += e[rr][u] * vv;
            }
        }
        #pragma unroll
        for (int rr = 0; rr < 8; ++rr)
            partials[kc * (TQ * DD) + (rb + rr) * DD + d] = acc[rr];
    }
    __syncthreads();

    // ---- reduce partials over 4 key-quarters, apply 1/l, write out ----
    {
        #pragma unroll
        for (int it = 0; it < 2; ++it) {
            const int idx = tid + it * 512;
            const int r  = idx >> 6;
            const int d2 = idx & 63;
            const float v = partials[idx] + partials[1024 + idx] +
                            partials[2048 + idx] + partials[3072 + idx];
            o_out[((size_t)bh * SS + q0 + r) * DD + d2] = v * invl[r];
        }
    }
}

extern "C" void kernel_launch(void* const* d_in, const int* in_sizes, int n_in,
                              void* d_out, int out_size, void* d_ws, size_t ws_size,
                              hipStream_t stream) {
    const float* q  = (const float*)d_in[0];
    const float* k  = (const float*)d_in[1];
    const float* v  = (const float*)d_in[2];
    const float* bw = (const float*)d_in[3];
    const int*   cp = (const int*)d_in[4];
    const int*   mp = (const int*)d_in[5];
    const int*   mask = (const int*)d_in[6];

    float* o_out = (float*)d_out;                                   // [B,H,S,D]
    float* a_out = o_out + (size_t)BB * HH * SS * DD;               // [B,H,S,S]
    float* p_out = a_out + (size_t)BB * HH * SS * SS;               // [B,H,S,S]

    const int grid = BB * HH * (SS / TQ);   // 4096 blocks, one per (b,h,q-tile)
    attn_tile_kernel<<<grid, 512, 0, stream>>>(q, k, v, bw, cp, mp, mask,
                                               o_out, a_out, p_out);
}